// Round 16
// baseline (182.142 us; speedup 1.0000x reference)
//
#include <hip/hip_runtime.h>
#include <hip/hip_bf16.h>
#include <math.h>

typedef float v2f __attribute__((ext_vector_type(2)));
typedef float v4f __attribute__((ext_vector_type(4)));
typedef float f32x8 __attribute__((ext_vector_type(8)));

// Problem constants
#define NQ1 1001      // NQ+1 rows in embed tables
#define KK 5
#define MM 50
#define KD 64
#define VD 64
#define SD 50
#define BB 512
#define SS 500

#define NW 8          // waves per scan block
#define WIN 8         // scan steps per window
#define NWIN 62       // full windows (62*8 = 496; tail = 4 steps = 2 pairs)

// Workspace layout (in floats)
#define OFF_ATTN   0                        // [1001][64] attn rows, cols 50..63 = 0
#define OFF_SQ     (OFF_ATTN + NQ1*64)      // [1001][64] q_embed @ Ws[64:128]
#define OFF_EAD    (OFF_SQ   + NQ1*64)      // [5005][128] interleaved (-e,ad) per v
#define OFF_WST    (OFF_EAD  + NQ1*KK*128)  // [50][64] transposed top of Ws
#define OFF_WCT    (OFF_WST  + SD*64)       // [5][50] transposed Wc (pad to 256)
#define OFF_READS  (OFF_WCT  + 256)         // [512*500][64]

#define LGKM_BARRIER() asm volatile("s_waitcnt lgkmcnt(0)\n\ts_barrier" ::: "memory")
#define SCHED_FENCE() __builtin_amdgcn_sched_barrier(0)
#define RL(x_) __builtin_amdgcn_readfirstlane(x_)

// scalar load of one 32B attn slice: dst (8 SGPRs) <- attn_tab + byteoff
#define SLOAD(dst_, off_) \
  asm volatile("s_load_dwordx8 %0, %1, %2" : "=s"(dst_) : "s"(attn_tab), "s"(off_))

// packed f32 ops; a_ is a wave-uniform SGPR pair (1 scalar read/instr allowed)
#define PK_MUL_S(d_, a_, b_) \
  asm("v_pk_mul_f32 %0, %1, %2" : "=v"(d_) : "s"(a_), "v"(b_))
#define PK_FMA_S(dc_, a_, b_) \
  asm("v_pk_fma_f32 %0, %1, %2, %0" : "+v"(dc_) : "s"(a_), "v"(b_))
// t = broadcast(ed.lo=-e) * vm + broadcast(ed.hi=ad)
#define PK_EAD(t_, ed_, vm_) \
  asm("v_pk_fma_f32 %0, %1, %2, %1 op_sel:[0,0,1] op_sel_hi:[0,1,1]" \
      : "=&v"(t_) : "v"(ed_), "v"(vm_))

// ---------------- kernel 1: all tables (qtab softmax+Sq, transposes, ead) ----------------
__global__ __launch_bounds__(64) void k_tabs(
    const float* __restrict__ qtab, const float* __restrict__ itab,
    const float* __restrict__ keymem,
    const float* __restrict__ Wv, const float* __restrict__ bv,
    const float* __restrict__ We, const float* __restrict__ be,
    const float* __restrict__ Wa, const float* __restrict__ ba,
    const float* __restrict__ Ws, const float* __restrict__ Wc,
    float* __restrict__ attn_tab, float* __restrict__ sq_tab,
    float* __restrict__ ead_tab, float* __restrict__ WsT, float* __restrict__ WcT) {
  const int bid = blockIdx.x;
  const int t = threadIdx.x;

  if (bid < NQ1) {  // ---- per-question: attn softmax row + sq row ----
    const int q = bid;
    __shared__ float qe[64];
    qe[t] = qtab[q * KD + t];
    __syncthreads();

    float dot = 0.f;
    if (t < MM) {
#pragma unroll
      for (int i = 0; i < KD; ++i) dot = fmaf(qe[i], keymem[t * KD + i], dot);
    }
    float xv = (t < MM) ? dot : -1e30f;
#pragma unroll
    for (int off = 32; off; off >>= 1) xv = fmaxf(xv, __shfl_xor(xv, off));
    float p = (t < MM) ? __expf(dot - xv) : 0.f;
    float sum = p;
#pragma unroll
    for (int off = 32; off; off >>= 1) sum += __shfl_xor(sum, off);
    attn_tab[q * 64 + t] = p / sum;   // pad lanes (t>=50) write 0

    float sq = 0.f;
    if (t < SD) {
#pragma unroll
      for (int i = 0; i < KD; ++i) sq = fmaf(qe[i], Ws[(64 + i) * SD + t], sq);
    }
    sq_tab[q * 64 + t] = (t < SD) ? sq : 0.f;
    return;
  }

  if (bid == NQ1) {  // ---- transposes ----
    for (int idx = t; idx < 64 * SD; idx += 64) {
      int i = idx / SD, j = idx % SD;
      WsT[j * 64 + i] = Ws[idx];
    }
    for (int idx = t; idx < SD * KK; idx += 64) {
      int j = idx / KK, c = idx % KK;
      WcT[c * SD + j] = Wc[idx];
    }
    return;
  }

  // ---- per-(q,r) erase/add, interleaved; NOTE: stores MINUS-e ----
  const int qr = bid - (NQ1 + 1);
  const int q = qr / KK, r = qr % KK;
  const int v = t;
  __shared__ float item[64];
  __shared__ float ves[64];
  item[v] = itab[q * KD + v];
  __syncthreads();

  float ve = bv[v];
#pragma unroll
  for (int i = 0; i < KD; ++i) ve = fmaf(item[i], Wv[i * VD + v], ve);
#pragma unroll
  for (int k = 0; k < KK; ++k) {
    float rf = fmaxf(0.f, 1.f - fabsf((float)k - (float)r) * 0.25f);
    ve = fmaf(rf, Wv[(KD + k) * VD + v], ve);
  }
  ves[v] = ve;
  __syncthreads();

  float se = be[v], sa = ba[v];
#pragma unroll
  for (int i = 0; i < VD; ++i) {
    float x = ves[i];
    se = fmaf(x, We[i * VD + v], se);
    sa = fmaf(x, Wa[i * VD + v], sa);
  }
  float ex = __expf(2.f * sa);
  ead_tab[qr * 128 + 2 * v]     = -1.f / (1.f + __expf(-se));   // -e
  ead_tab[qr * 128 + 2 * v + 1] = (ex - 1.f) / (ex + 1.f);      // ad
}

// ---------------- kernel 2: scan (R15 skeleton + forced VOP3P pk math) ----------------
__global__ __launch_bounds__(512) void k_scan(
    const int* __restrict__ qs, const int* __restrict__ rs,
    const float* __restrict__ attn_tab, const float* __restrict__ ead_tab,
    const float* __restrict__ init_vm, float* __restrict__ reads) {
  const int b = blockIdx.x;
  const int tid = threadIdx.x;
  const int w = tid >> 6;       // wave id 0..7 (m-slots w*8 .. w*8+7)
  const int v = tid & 63;       // value column
  const int mbase = w * 8;
  const int wb = w << 5;        // byte offset of wave's slice within a row

  __shared__ v2f   red2[2][4][NW][64];      // 32 KB paired read partials
  __shared__ v4f   eadbuf[2][4][64];        // 8 KB (-e0,ad0,-e1,ad1) per pair
  __shared__ __align__(16) int sidx_a[512]; // 2 KB per-step attn byte offsets

  const int* __restrict__ qb = qs + b * SS;
  const int* __restrict__ rb = rs + b * SS;
  float* __restrict__ outp = reads + (size_t)b * SS * 64;

  // ---- fill per-step attn byte offsets (entries 500..511 clamped) ----
  {
    int idx = (tid < SS) ? tid : (SS - 1);
    sidx_a[tid] = qb[idx] << 8;
  }

  // ---- prologue: waves 4-7 stage window 0 ead pairs; prefetch window-1 q/r ----
  const int pp = w - 4;          // staging pair id for waves 4-7
  int q1a = 0, r1a = 0, q1b = 0, r1b = 0;
  if (w >= 4) {
    int qa = qb[2 * pp],     ra = rb[2 * pp];
    int qc = qb[2 * pp + 1], rc = rb[2 * pp + 1];
    float2 ea = *(const float2*)(ead_tab + (qa * KK + ra) * 128 + 2 * v);
    float2 eb = *(const float2*)(ead_tab + (qc * KK + rc) * 128 + 2 * v);
    eadbuf[0][pp][v] = (v4f){ea.x, ea.y, eb.x, eb.y};
    q1a = qb[8 + 2 * pp];     r1a = rb[8 + 2 * pp];
    q1b = qb[8 + 2 * pp + 1]; r1b = rb[8 + 2 * pp + 1];
  }

  v2f vm0, vm1, vm2, vm3;
  {
    int m = mbase;
    vm0.x = init_vm[(m + 0) * VD + v]; vm0.y = init_vm[(m + 1) * VD + v];
    vm1.x = init_vm[(m + 2) * VD + v]; vm1.y = init_vm[(m + 3) * VD + v];
    if (m + 4 < MM) { vm2.x = init_vm[(m + 4) * VD + v]; vm2.y = init_vm[(m + 5) * VD + v]; }
    else vm2 = (v2f)(0.f);
    if (m + 6 < MM) { vm3.x = init_vm[(m + 6) * VD + v]; vm3.y = init_vm[(m + 7) * VD + v]; }
    else vm3 = (v2f)(0.f);
  }
  __syncthreads();   // sidx_a + eadbuf[0] visible

  // ---- load window-0 a-slices into SGPR buffer (8 x s_load_dwordx8) ----
  f32x8 arow[8];
  {
    int4 p0 = *(const int4*)&sidx_a[0];
    int4 p1 = *(const int4*)&sidx_a[4];
    uint32_t o0 = RL(p0.x + wb), o1 = RL(p0.y + wb);
    uint32_t o2 = RL(p0.z + wb), o3 = RL(p0.w + wb);
    uint32_t o4 = RL(p1.x + wb), o5 = RL(p1.y + wb);
    uint32_t o6 = RL(p1.z + wb), o7 = RL(p1.w + wb);
    SLOAD(arow[0], o0); SLOAD(arow[1], o1); SLOAD(arow[2], o2); SLOAD(arow[3], o3);
    SLOAD(arow[4], o4); SLOAD(arow[5], o5); SLOAD(arow[6], o6); SLOAD(arow[7], o7);
  }
  LGKM_BARRIER();
  SCHED_FENCE();

  v4f edp[2];

  // one step: a from SGPR pairs, ed = packed(-e,ad) broadcast via op_sel
#define HALFSTEP(kk_, edv_, accv_) {                                 \
    v2f a0 = {arow[kk_][0], arow[kk_][1]};                           \
    v2f a1 = {arow[kk_][2], arow[kk_][3]};                           \
    v2f a2 = {arow[kk_][4], arow[kk_][5]};                           \
    v2f a3 = {arow[kk_][6], arow[kk_][7]};                           \
    v2f acc, t0, t1, t2, t3;                                         \
    PK_MUL_S(acc, a0, vm0);                                          \
    PK_EAD(t0, edv_, vm0);                                           \
    PK_FMA_S(vm0, a0, t0);                                           \
    PK_FMA_S(acc, a1, vm1);                                          \
    PK_EAD(t1, edv_, vm1);                                           \
    PK_FMA_S(vm1, a1, t1);                                           \
    PK_FMA_S(acc, a2, vm2);                                          \
    PK_EAD(t2, edv_, vm2);                                           \
    PK_FMA_S(vm2, a2, t2);                                           \
    PK_FMA_S(acc, a3, vm3);                                          \
    PK_EAD(t3, edv_, vm3);                                           \
    PK_FMA_S(vm3, a3, t3);                                           \
    accv_ = acc.x + acc.y;                                           \
  }

  // PAIR p: steps 2p,2p+1; consumes edp ring; reloads arow slots for next window
#define PAIR(buf_, p_) {                                             \
    v4f ed = edp[(p_) & 1];                                          \
    if ((p_) < 2) edp[(p_) & 1] = eadbuf[buf_][(p_) + 2][v];         \
    v2f edA = {ed.x, ed.y};                                          \
    v2f edB = {ed.z, ed.w};                                          \
    float accA, accB;                                                \
    HALFSTEP(2 * (p_), edA, accA)                                    \
    SLOAD(arow[2 * (p_)], onext##p_##a);                             \
    HALFSTEP(2 * (p_) + 1, edB, accB)                                \
    SLOAD(arow[2 * (p_) + 1], onext##p_##b);                         \
    red2[buf_][p_][w][v] = (v2f){accA, accB};                        \
  }

  for (int wi = 0; wi < NWIN; ++wi) {
    const int buf = wi & 1;
    const int nb = buf ^ 1;

    // next-window a byte offsets (uniform b128 reads + readfirstlane)
    int4 p0 = *(const int4*)&sidx_a[(wi + 1) * 8];
    int4 p1 = *(const int4*)&sidx_a[(wi + 1) * 8 + 4];
    uint32_t onext0a = RL(p0.x + wb), onext0b = RL(p0.y + wb);
    uint32_t onext1a = RL(p0.z + wb), onext1b = RL(p0.w + wb);
    uint32_t onext2a = RL(p1.x + wb), onext2b = RL(p1.y + wb);
    uint32_t onext3a = RL(p1.z + wb), onext3b = RL(p1.w + wb);

    // edp preload for pairs 0,1
    edp[0] = eadbuf[buf][0][v];
    edp[1] = eadbuf[buf][1][v];

    // role-split window work:
    float2 ea_st, eb_st;
    if (w >= 4) {
      // staging waves: gather window wi+1's ead pair (VMEM, consumed post-STEPs)
      ea_st = *(const float2*)(ead_tab + (q1a * KK + r1a) * 128 + 2 * v);
      eb_st = *(const float2*)(ead_tab + (q1b * KK + r1b) * 128 + 2 * v);
      // prefetch q/r for window wi+2
      int i2 = (wi + 2) * 8 + 2 * pp;
      int i2a = (i2 < SS) ? i2 : (SS - 1);
      int i2b = (i2 + 1 < SS) ? (i2 + 1) : (SS - 1);
      q1a = qb[i2a]; r1a = rb[i2a];
      q1b = qb[i2b]; r1b = rb[i2b];
    } else if (wi > 0) {
      // flush waves: pair w of window wi-1 -> rows (wi-1)*8 + 2w, +1
      v2f s = (v2f)(0.f);
#pragma unroll
      for (int wv = 0; wv < NW; ++wv) s += red2[nb][w][wv][v];
      size_t rowb = (size_t)((wi - 1) * WIN + 2 * w) * 64 + v;
      outp[rowb] = s.x;
      outp[rowb + 64] = s.y;
    }

    // compute 4 pairs (8 steps)
    PAIR(buf, 0) PAIR(buf, 1) PAIR(buf, 2) PAIR(buf, 3)

    // staging write (waves 4-7)
    if (w >= 4) eadbuf[nb][pp][v] = (v4f){ea_st.x, ea_st.y, eb_st.x, eb_st.y};

    LGKM_BARRIER();   // drains LDS ops + this window's s_loads
    SCHED_FENCE();
  }

  // ---- tail: window 62 = steps 496..499 (pairs 0,1), buf 0 ----
  {
    uint32_t onext0a, onext0b, onext1a, onext1b;
    {
      int4 p0 = *(const int4*)&sidx_a[504];   // clamped entries, harmless reloads
      onext0a = RL(p0.x + wb); onext0b = RL(p0.y + wb);
      onext1a = RL(p0.z + wb); onext1b = RL(p0.w + wb);
    }
    edp[0] = eadbuf[0][0][v];
    edp[1] = eadbuf[0][1][v];
    if (w < 4) {                 // flush window 61 (red2[1])
      v2f s = (v2f)(0.f);
#pragma unroll
      for (int wv = 0; wv < NW; ++wv) s += red2[1][w][wv][v];
      size_t rowb = (size_t)((NWIN - 1) * WIN + 2 * w) * 64 + v;
      outp[rowb] = s.x;
      outp[rowb + 64] = s.y;
    }
    PAIR(0, 0) PAIR(0, 1)
    LGKM_BARRIER();
    SCHED_FENCE();
    if (w < 2) {                 // final flush: rows 496..499
      v2f s = (v2f)(0.f);
#pragma unroll
      for (int wv = 0; wv < NW; ++wv) s += red2[0][w][wv][v];
      size_t rowb = (size_t)(NWIN * WIN + 2 * w) * 64 + v;
      outp[rowb] = s.x;
      outp[rowb + 64] = s.y;
    }
  }
#undef PAIR
#undef HALFSTEP
}

// ---------------- kernel 3: summary + logits + softmax ----------------
__global__ __launch_bounds__(64) void k_out(
    const float* __restrict__ reads, const int* __restrict__ qs,
    const float* __restrict__ sq_tab, const float* __restrict__ WsT,
    const float* __restrict__ bs, const float* __restrict__ WcT,
    const float* __restrict__ bc,
    float* __restrict__ out_logits, float* __restrict__ out_probs) {
  __shared__ float xs[64 * 65];
  const int lane = threadIdx.x;
  const long rowbase = (long)blockIdx.x * 64;
  const float* __restrict__ src = reads + rowbase * 64;

#pragma unroll 8
  for (int it = 0; it < 64; ++it)
    xs[it * 65 + lane] = src[it * 64 + lane];
  __syncthreads();

  float x[64];
#pragma unroll
  for (int i = 0; i < 64; ++i) x[i] = xs[lane * 65 + i];

  const long row = rowbase + lane;
  const int q = qs[row];
  const float* __restrict__ sqrow = sq_tab + (long)q * 64;

  float sm[SD];
#pragma unroll
  for (int j = 0; j < SD; ++j) {
    float acc = bs[j] + sqrow[j];
    const float* __restrict__ wrow = WsT + j * 64;  // uniform -> s_load
#pragma unroll
    for (int i = 0; i < 64; ++i) acc = fmaf(x[i], wrow[i], acc);
    float ex = __expf(2.f * acc);
    sm[j] = (ex - 1.f) / (ex + 1.f);
  }

  float lg[KK];
#pragma unroll
  for (int c = 0; c < KK; ++c) {
    float acc = bc[c];
    const float* __restrict__ wrow = WcT + c * SD;  // uniform -> s_load
#pragma unroll
    for (int j = 0; j < SD; ++j) acc = fmaf(sm[j], wrow[j], acc);
    lg[c] = acc;
  }

  float mx = lg[0];
#pragma unroll
  for (int c = 1; c < KK; ++c) mx = fmaxf(mx, lg[c]);
  float p[KK], sum = 0.f;
#pragma unroll
  for (int c = 0; c < KK; ++c) { p[c] = __expf(lg[c] - mx); sum += p[c]; }
  float inv = 1.f / sum;
#pragma unroll
  for (int c = 0; c < KK; ++c) {
    out_logits[row * KK + c] = lg[c];
    out_probs[row * KK + c] = p[c] * inv;
  }
}

extern "C" void kernel_launch(void* const* d_in, const int* in_sizes, int n_in,
                              void* d_out, int out_size, void* d_ws, size_t ws_size,
                              hipStream_t stream) {
  const int*   questions  = (const int*)  d_in[0];
  const int*   responses  = (const int*)  d_in[1];
  const float* q_table    = (const float*)d_in[2];
  const float* item_table = (const float*)d_in[3];
  const float* Wv         = (const float*)d_in[4];
  const float* bv         = (const float*)d_in[5];
  const float* key_mem    = (const float*)d_in[6];
  const float* init_vm    = (const float*)d_in[7];
  const float* We         = (const float*)d_in[8];
  const float* be         = (const float*)d_in[9];
  const float* Wa         = (const float*)d_in[10];
  const float* ba         = (const float*)d_in[11];
  const float* Ws         = (const float*)d_in[12];
  const float* bs         = (const float*)d_in[13];
  const float* Wc         = (const float*)d_in[14];
  const float* bc         = (const float*)d_in[15];

  float* ws       = (float*)d_ws;
  float* attn_tab = ws + OFF_ATTN;
  float* sq_tab   = ws + OFF_SQ;
  float* ead_tab  = ws + OFF_EAD;
  float* WsT      = ws + OFF_WST;
  float* WcT      = ws + OFF_WCT;
  float* reads    = ws + OFF_READS;

  float* out_logits = (float*)d_out;
  float* out_probs  = out_logits + (size_t)BB * SS * KK;

  hipLaunchKernelGGL(k_tabs, dim3(NQ1 + 1 + NQ1 * KK), dim3(64), 0, stream,
                     q_table, item_table, key_mem, Wv, bv, We, be, Wa, ba, Ws, Wc,
                     attn_tab, sq_tab, ead_tab, WsT, WcT);
  hipLaunchKernelGGL(k_scan, dim3(BB), dim3(NW * 64), 0, stream,
                     questions, responses, attn_tab, ead_tab, init_vm, reads);
  hipLaunchKernelGGL(k_out, dim3(BB * SS / 64), dim3(64), 0, stream,
                     reads, questions, sq_tab, WsT, bs, WcT, bc,
                     out_logits, out_probs);
}

// Round 17
// 158.792 us; speedup vs baseline: 1.1470x; 1.1470x over previous
//
#include <hip/hip_runtime.h>
#include <hip/hip_bf16.h>
#include <math.h>

typedef float v2f __attribute__((ext_vector_type(2)));
typedef float f32x8 __attribute__((ext_vector_type(8)));

// Problem constants
#define NQ1 1001      // NQ+1 rows in embed tables
#define KK 5
#define MM 50
#define KD 64
#define VD 64
#define SD 50
#define BB 512
#define SS 500

#define NW 8          // waves per scan block
#define WIN 8         // scan steps per window
#define NWIN 62       // full windows (62*8 = 496; tail = 4 steps)

// Workspace layout (in floats)
#define OFF_ATTN   0                        // [1001][64] attn rows, cols 50..63 = 0
#define OFF_SQ     (OFF_ATTN + NQ1*64)      // [1001][64] q_embed @ Ws[64:128]
#define OFF_EAD    (OFF_SQ   + NQ1*64)      // [5005][128] interleaved (e,ad) per v
#define OFF_WST    (OFF_EAD  + NQ1*KK*128)  // [50][64] transposed top of Ws
#define OFF_WCT    (OFF_WST  + SD*64)       // [5][50] transposed Wc (pad to 256)
#define OFF_READS  (OFF_WCT  + 256)         // [512*500][64]
// transient per-q/per-r tables carved out of the reads area (consumed by
// k_tabsB BEFORE k_scan overwrites reads):
#define OFF_SEQ    (OFF_READS)              // [1001][64]  (item@Wv+bv)@We + be
#define OFF_SAQ    (OFF_SEQ + NQ1*64)       // [1001][64]  (item@Wv+bv)@Wa + ba
#define OFF_RPE    (OFF_SAQ + NQ1*64)       // [5][64]     rf[r]@(Wv_resp@We)
#define OFF_RPA    (OFF_RPE + 5*64)         // [5][64]

#define LGKM_BARRIER() asm volatile("s_waitcnt lgkmcnt(0)\n\ts_barrier" ::: "memory")
#define SCHED_FENCE() __builtin_amdgcn_sched_barrier(0)
#define RL(x_) __builtin_amdgcn_readfirstlane(x_)

// scalar load of one 32B attn slice: dst (8 SGPRs) <- attn_tab + byteoff
#define SLOAD(dst_, off_) \
  asm volatile("s_load_dwordx8 %0, %1, %2" : "=s"(dst_) : "s"(attn_tab), "s"(off_))

// ---------------- kernel 1a: per-q tables + transposes + per-r tables ----------------
__global__ __launch_bounds__(64) void k_tabsA(
    const float* __restrict__ qtab, const float* __restrict__ itab,
    const float* __restrict__ keymem,
    const float* __restrict__ Wv, const float* __restrict__ bv,
    const float* __restrict__ We, const float* __restrict__ be,
    const float* __restrict__ Wa, const float* __restrict__ ba,
    const float* __restrict__ Ws, const float* __restrict__ Wc,
    float* __restrict__ attn_tab, float* __restrict__ sq_tab,
    float* __restrict__ WsT, float* __restrict__ WcT,
    float* __restrict__ seq, float* __restrict__ saq,
    float* __restrict__ rpe, float* __restrict__ rpa) {
  const int bid = blockIdx.x;
  const int t = threadIdx.x;

  if (bid < NQ1) {  // ---- per-question: attn softmax, sq, seq/saq rows ----
    const int q = bid;
    __shared__ float qe[64];
    __shared__ float item[64];
    __shared__ float vq[64];
    qe[t] = qtab[q * KD + t];
    item[t] = itab[q * KD + t];
    __syncthreads();

    float dot = 0.f;
    if (t < MM) {
#pragma unroll
      for (int i = 0; i < KD; ++i) dot = fmaf(qe[i], keymem[t * KD + i], dot);
    }
    float xv = (t < MM) ? dot : -1e30f;
#pragma unroll
    for (int off = 32; off; off >>= 1) xv = fmaxf(xv, __shfl_xor(xv, off));
    float p = (t < MM) ? __expf(dot - xv) : 0.f;
    float sum = p;
#pragma unroll
    for (int off = 32; off; off >>= 1) sum += __shfl_xor(sum, off);
    attn_tab[q * 64 + t] = p / sum;   // pad lanes (t>=50) write 0

    float sq = 0.f;
    if (t < SD) {
#pragma unroll
      for (int i = 0; i < KD; ++i) sq = fmaf(qe[i], Ws[(64 + i) * SD + t], sq);
    }
    sq_tab[q * 64 + t] = (t < SD) ? sq : 0.f;

    // vq = item @ Wv + bv (the q-only part of value_embed)
    float v0 = bv[t];
#pragma unroll
    for (int i = 0; i < KD; ++i) v0 = fmaf(item[i], Wv[i * VD + t], v0);
    vq[t] = v0;
    __syncthreads();

    // seq = vq @ We + be ; saq = vq @ Wa + ba
    float se = be[t], sa = ba[t];
#pragma unroll
    for (int i = 0; i < VD; ++i) {
      float x = vq[i];
      se = fmaf(x, We[i * VD + t], se);
      sa = fmaf(x, Wa[i * VD + t], sa);
    }
    seq[q * 64 + t] = se;
    saq[q * 64 + t] = sa;
    return;
  }

  if (bid == NQ1) {  // ---- transposes ----
    for (int idx = t; idx < 64 * SD; idx += 64) {
      int i = idx / SD, j = idx % SD;
      WsT[j * 64 + i] = Ws[idx];
    }
    for (int idx = t; idx < SD * KK; idx += 64) {
      int j = idx / KK, c = idx % KK;
      WcT[c * SD + j] = Wc[idx];
    }
    return;
  }

  // ---- bid == NQ1+1: per-r tables rpe/rpa = rf[r] @ (Wv_resp @ {We,Wa}) ----
  __shared__ float wrW[KK][64];
  __shared__ float wrA[KK][64];
#pragma unroll
  for (int k = 0; k < KK; ++k) {
    float accW = 0.f, accA = 0.f;
#pragma unroll
    for (int i = 0; i < VD; ++i) {
      float wv = Wv[(KD + k) * VD + i];
      accW = fmaf(wv, We[i * VD + t], accW);
      accA = fmaf(wv, Wa[i * VD + t], accA);
    }
    wrW[k][t] = accW;
    wrA[k][t] = accA;
  }
  __syncthreads();
#pragma unroll
  for (int r = 0; r < KK; ++r) {
    float pe = 0.f, pa = 0.f;
#pragma unroll
    for (int k = 0; k < KK; ++k) {
      float rf = fmaxf(0.f, 1.f - fabsf((float)k - (float)r) * 0.25f);
      pe = fmaf(rf, wrW[k][t], pe);
      pa = fmaf(rf, wrA[k][t], pa);
    }
    rpe[r * 64 + t] = pe;
    rpa[r * 64 + t] = pa;
  }
}

// ---------------- kernel 1b: ead rows = activation(per-q part + per-r part) ----------------
__global__ __launch_bounds__(64) void k_tabsB(
    const float* __restrict__ seq, const float* __restrict__ saq,
    const float* __restrict__ rpe, const float* __restrict__ rpa,
    float* __restrict__ ead_tab) {
  const int qr = blockIdx.x;
  const int q = qr / KK, r = qr % KK;
  const int v = threadIdx.x;
  float se = seq[q * 64 + v] + rpe[r * 64 + v];
  float sa = saq[q * 64 + v] + rpa[r * 64 + v];
  float ex = __expf(2.f * sa);
  ead_tab[qr * 128 + 2 * v]     = 1.f / (1.f + __expf(-se));
  ead_tab[qr * 128 + 2 * v + 1] = (ex - 1.f) / (ex + 1.f);
}

// ---------------- kernel 2: scan (R14: SGPR a-rows + LDS ead/red, lgkm barriers) ----------------
__global__ __launch_bounds__(512) void k_scan(
    const int* __restrict__ qs, const int* __restrict__ rs,
    const float* __restrict__ attn_tab, const float* __restrict__ ead_tab,
    const float* __restrict__ init_vm, float* __restrict__ reads) {
  const int b = blockIdx.x;
  const int tid = threadIdx.x;
  const int w = tid >> 6;       // wave id 0..7 (m-slots w*8 .. w*8+7)
  const int v = tid & 63;       // value column
  const int mbase = w * 8;
  const int wb = w << 5;        // byte offset of wave's slice within a row

  __shared__ float red[2][WIN][NW][64];     // 32 KB partial read sums
  __shared__ v2f   eadbuf[2][WIN][64];      // 8 KB interleaved (e,ad) per v
  __shared__ __align__(16) int sidx_a[512]; // 2 KB per-step attn byte offsets

  const int* __restrict__ qb = qs + b * SS;
  const int* __restrict__ rb = rs + b * SS;
  float* __restrict__ outp = reads + (size_t)b * SS * 64;

  // ---- fill per-step attn byte offsets (entries 500..511 clamped) ----
  {
    int idx = (tid < SS) ? tid : (SS - 1);
    sidx_a[tid] = qb[idx] << 8;
  }

  // ---- prologue: stage window 0 ead; preload q/r ring for window 1 ----
  {
    int qp = qb[w], rp = rb[w];
    float2 ep = *(const float2*)(ead_tab + (qp * KK + rp) * 128 + 2 * v);
    eadbuf[0][w][v] = (v2f){ep.x, ep.y};
  }
  int q1 = qb[8 + w], r1 = rb[8 + w];

  v2f vm0, vm1, vm2, vm3;
  {
    int m = mbase;
    vm0.x = init_vm[(m + 0) * VD + v]; vm0.y = init_vm[(m + 1) * VD + v];
    vm1.x = init_vm[(m + 2) * VD + v]; vm1.y = init_vm[(m + 3) * VD + v];
    if (m + 4 < MM) { vm2.x = init_vm[(m + 4) * VD + v]; vm2.y = init_vm[(m + 5) * VD + v]; }
    else vm2 = (v2f)(0.f);
    if (m + 6 < MM) { vm3.x = init_vm[(m + 6) * VD + v]; vm3.y = init_vm[(m + 7) * VD + v]; }
    else vm3 = (v2f)(0.f);
  }
  __syncthreads();   // sidx_a visible to all waves

  // ---- load window-0 a-slices into SGPR buffer (8 x s_load_dwordx8) ----
  f32x8 arow[8];
  {
    int4 p0 = *(const int4*)&sidx_a[0];
    int4 p1 = *(const int4*)&sidx_a[4];
    uint32_t o0 = RL(p0.x + wb), o1 = RL(p0.y + wb);
    uint32_t o2 = RL(p0.z + wb), o3 = RL(p0.w + wb);
    uint32_t o4 = RL(p1.x + wb), o5 = RL(p1.y + wb);
    uint32_t o6 = RL(p1.z + wb), o7 = RL(p1.w + wb);
    SLOAD(arow[0], o0); SLOAD(arow[1], o1); SLOAD(arow[2], o2); SLOAD(arow[3], o3);
    SLOAD(arow[4], o4); SLOAD(arow[5], o5); SLOAD(arow[6], o6); SLOAD(arow[7], o7);
  }
  LGKM_BARRIER();   // drains s_loads + eadbuf staging
  SCHED_FENCE();

  v2f edr[2];

#define STEP(buf_, kk) {                                             \
    v2f ed = edr[(kk) & 1];                                          \
    if ((kk) < WIN - 2) edr[(kk) & 1] = eadbuf[buf_][(kk) + 2][v];   \
    v2f e2 = {ed.x, ed.x}, ad2 = {ed.y, ed.y};                       \
    v2f aL0 = {arow[kk][0], arow[kk][1]};                            \
    v2f aL1 = {arow[kk][2], arow[kk][3]};                            \
    v2f aH0 = {arow[kk][4], arow[kk][5]};                            \
    v2f aH1 = {arow[kk][6], arow[kk][7]};                            \
    v2f acc;                                                         \
    acc  = aL0 * vm0;  vm0 += aL0 * (ad2 - e2 * vm0);                \
    acc += aL1 * vm1;  vm1 += aL1 * (ad2 - e2 * vm1);                \
    acc += aH0 * vm2;  vm2 += aH0 * (ad2 - e2 * vm2);                \
    acc += aH1 * vm3;  vm3 += aH1 * (ad2 - e2 * vm3);                \
    red[buf_][kk][w][v] = acc.x + acc.y;                             \
    SLOAD(arow[kk], onext##kk);                                      \
  }

#define FLUSH(pbuf_, baserow_) {                                     \
    float sum = 0.f;                                                 \
    _Pragma("unroll")                                                \
    for (int wv = 0; wv < NW; ++wv) sum += red[pbuf_][w][wv][v];     \
    outp[(size_t)((baserow_) + w) * 64 + v] = sum;                   \
  }

  for (int wi = 0; wi < NWIN; ++wi) {
    const int buf = wi & 1;
    const int nb = buf ^ 1;

    // next-window a byte offsets (uniform b128 reads + readfirstlane)
    int4 p0 = *(const int4*)&sidx_a[(wi + 1) * 8];
    int4 p1 = *(const int4*)&sidx_a[(wi + 1) * 8 + 4];
    uint32_t onext0 = RL(p0.x + wb), onext1 = RL(p0.y + wb);
    uint32_t onext2 = RL(p0.z + wb), onext3 = RL(p0.w + wb);
    uint32_t onext4 = RL(p1.x + wb), onext5 = RL(p1.y + wb);
    uint32_t onext6 = RL(p1.z + wb), onext7 = RL(p1.w + wb);

    // edr preload for steps 0,1
    edr[0] = eadbuf[buf][0][v];
    edr[1] = eadbuf[buf][1][v];

    // flush previous window (reads red[nb]; store fire-and-forget)
    if (wi > 0) FLUSH(nb, (wi - 1) * WIN);

    // ead staging issue for window wi+1 (VMEM)
    float2 e_st = *(const float2*)(ead_tab + (q1 * KK + r1) * 128 + 2 * v);
    int i2 = (wi + 2) * WIN + w;
    i2 = (i2 < SS) ? i2 : (SS - 1);
    int q2 = qb[i2], r2 = rb[i2];

    // 8 steps; each consumes arow[k] then reloads it for window wi+1
    STEP(buf, 0) STEP(buf, 1) STEP(buf, 2) STEP(buf, 3)
    STEP(buf, 4) STEP(buf, 5) STEP(buf, 6) STEP(buf, 7)

    // ead staging write
    eadbuf[nb][w][v] = (v2f){e_st.x, e_st.y};
    q1 = q2; r1 = r2;

    LGKM_BARRIER();   // drains LDS ops AND this window's s_loads
    SCHED_FENCE();
  }

  // ---- tail: window 62 = steps 496..499, buf 0 (arow loaded in window 61) ----
  {
    uint32_t onext0, onext1, onext2, onext3;
    {
      int4 p0 = *(const int4*)&sidx_a[504];   // clamped entries, harmless reloads
      onext0 = RL(p0.x + wb); onext1 = RL(p0.y + wb);
      onext2 = RL(p0.z + wb); onext3 = RL(p0.w + wb);
    }
    edr[0] = eadbuf[0][0][v];
    edr[1] = eadbuf[0][1][v];
    FLUSH(1, (NWIN - 1) * WIN);              // flush window 61
    STEP(0, 0) STEP(0, 1) STEP(0, 2) STEP(0, 3)
    LGKM_BARRIER();
    SCHED_FENCE();
    if (w < (SS - NWIN * WIN)) {
      float sum = 0.f;
#pragma unroll
      for (int wv = 0; wv < NW; ++wv) sum += red[0][w][wv][v];
      outp[(size_t)(NWIN * WIN + w) * 64 + v] = sum;
    }
  }
#undef STEP
#undef FLUSH
}

// ---------------- kernel 3: summary + logits + softmax (packed f32) ----------------
__global__ __launch_bounds__(64) void k_out(
    const float* __restrict__ reads, const int* __restrict__ qs,
    const float* __restrict__ sq_tab, const float* __restrict__ WsT,
    const float* __restrict__ bs, const float* __restrict__ WcT,
    const float* __restrict__ bc,
    float* __restrict__ out_logits, float* __restrict__ out_probs) {
  __shared__ float xs[64 * 65];
  const int lane = threadIdx.x;
  const long rowbase = (long)blockIdx.x * 64;
  const float* __restrict__ src = reads + rowbase * 64;

#pragma unroll 8
  for (int it = 0; it < 64; ++it)
    xs[it * 65 + lane] = src[it * 64 + lane];
  __syncthreads();

  v2f x2[32];
#pragma unroll
  for (int i = 0; i < 32; ++i)
    x2[i] = (v2f){xs[lane * 65 + 2 * i], xs[lane * 65 + 2 * i + 1]};

  const long row = rowbase + lane;
  const int q = qs[row];
  const float* __restrict__ sqrow = sq_tab + (long)q * 64;

  __attribute__((aligned(8))) float sm[SD];
#pragma unroll
  for (int j = 0; j < SD; ++j) {
    const v2f* __restrict__ wr2 = (const v2f*)(WsT + j * 64);  // uniform -> s_load
    v2f acc2 = (v2f)(0.f);
#pragma unroll
    for (int i = 0; i < 32; ++i) acc2 += x2[i] * wr2[i];
    float acc = acc2.x + acc2.y + bs[j] + sqrow[j];
    float ex = __expf(2.f * acc);
    sm[j] = (ex - 1.f) / (ex + 1.f);
  }

  float lg[KK];
  const v2f* __restrict__ sm2 = (const v2f*)sm;
#pragma unroll
  for (int c = 0; c < KK; ++c) {
    const v2f* __restrict__ wc2 = (const v2f*)(WcT + c * SD);  // uniform -> s_load
    v2f a2 = (v2f)(0.f);
#pragma unroll
    for (int j = 0; j < 25; ++j) a2 += sm2[j] * wc2[j];
    lg[c] = a2.x + a2.y + bc[c];
  }

  float mx = lg[0];
#pragma unroll
  for (int c = 1; c < KK; ++c) mx = fmaxf(mx, lg[c]);
  float p[KK], sum = 0.f;
#pragma unroll
  for (int c = 0; c < KK; ++c) { p[c] = __expf(lg[c] - mx); sum += p[c]; }
  float inv = 1.f / sum;
#pragma unroll
  for (int c = 0; c < KK; ++c) {
    out_logits[row * KK + c] = lg[c];
    out_probs[row * KK + c] = p[c] * inv;
  }
}

extern "C" void kernel_launch(void* const* d_in, const int* in_sizes, int n_in,
                              void* d_out, int out_size, void* d_ws, size_t ws_size,
                              hipStream_t stream) {
  const int*   questions  = (const int*)  d_in[0];
  const int*   responses  = (const int*)  d_in[1];
  const float* q_table    = (const float*)d_in[2];
  const float* item_table = (const float*)d_in[3];
  const float* Wv         = (const float*)d_in[4];
  const float* bv         = (const float*)d_in[5];
  const float* key_mem    = (const float*)d_in[6];
  const float* init_vm    = (const float*)d_in[7];
  const float* We         = (const float*)d_in[8];
  const float* be         = (const float*)d_in[9];
  const float* Wa         = (const float*)d_in[10];
  const float* ba         = (const float*)d_in[11];
  const float* Ws         = (const float*)d_in[12];
  const float* bs         = (const float*)d_in[13];
  const float* Wc         = (const float*)d_in[14];
  const float* bc         = (const float*)d_in[15];

  float* ws       = (float*)d_ws;
  float* attn_tab = ws + OFF_ATTN;
  float* sq_tab   = ws + OFF_SQ;
  float* ead_tab  = ws + OFF_EAD;
  float* WsT      = ws + OFF_WST;
  float* WcT      = ws + OFF_WCT;
  float* reads    = ws + OFF_READS;
  float* seq      = ws + OFF_SEQ;   // transient, inside reads area
  float* saq      = ws + OFF_SAQ;
  float* rpe      = ws + OFF_RPE;
  float* rpa      = ws + OFF_RPA;

  float* out_logits = (float*)d_out;
  float* out_probs  = out_logits + (size_t)BB * SS * KK;

  hipLaunchKernelGGL(k_tabsA, dim3(NQ1 + 2), dim3(64), 0, stream,
                     q_table, item_table, key_mem, Wv, bv, We, be, Wa, ba, Ws, Wc,
                     attn_tab, sq_tab, WsT, WcT, seq, saq, rpe, rpa);
  hipLaunchKernelGGL(k_tabsB, dim3(NQ1 * KK), dim3(64), 0, stream,
                     seq, saq, rpe, rpa, ead_tab);
  hipLaunchKernelGGL(k_scan, dim3(BB), dim3(NW * 64), 0, stream,
                     questions, responses, attn_tab, ead_tab, init_vm, reads);
  hipLaunchKernelGGL(k_out, dim3(BB * SS / 64), dim3(64), 0, stream,
                     reads, questions, sq_tab, WsT, bs, WcT, bc,
                     out_logits, out_probs);
}

// Round 18
// 156.063 us; speedup vs baseline: 1.1671x; 1.0175x over previous
//
#include <hip/hip_runtime.h>
#include <hip/hip_bf16.h>
#include <math.h>

typedef float v2f __attribute__((ext_vector_type(2)));
typedef float f32x8 __attribute__((ext_vector_type(8)));

// Problem constants
#define NQ1 1001      // NQ+1 rows in embed tables
#define KK 5
#define MM 50
#define KD 64
#define VD 64
#define SD 50
#define BB 512
#define SS 500

#define NW 8          // waves per scan block
#define WIN 8         // scan steps per window
#define NWIN 62       // full windows (62*8 = 496; tail = 4 steps)

// Workspace layout (in floats)
#define OFF_ATTN   0                        // [1001][64] attn rows, cols 50..63 = 0
#define OFF_SQ     (OFF_ATTN + NQ1*64)      // [1001][64] q_embed @ Ws[64:128]
#define OFF_EAD    (OFF_SQ   + NQ1*64)      // [5005][128] interleaved (e,ad) per v
#define OFF_WST    (OFF_EAD  + NQ1*KK*128)  // [50][64] transposed top of Ws
#define OFF_WCT    (OFF_WST  + SD*64)       // [5][50] transposed Wc (pad to 256)
#define OFF_READS  (OFF_WCT  + 256)         // [512*500][64]

#define LGKM_BARRIER() asm volatile("s_waitcnt lgkmcnt(0)\n\ts_barrier" ::: "memory")
#define SCHED_FENCE() __builtin_amdgcn_sched_barrier(0)
#define RL(x_) __builtin_amdgcn_readfirstlane(x_)

// scalar load of one 32B attn slice: dst (8 SGPRs) <- attn_tab + byteoff
#define SLOAD(dst_, off_) \
  asm volatile("s_load_dwordx8 %0, %1, %2" : "=s"(dst_) : "s"(attn_tab), "s"(off_))

// ---------------- kernel 1: all tables, fused (per-q: attn/sq/ead rows; +transposes) ----------------
__global__ __launch_bounds__(64) void k_tabs(
    const float* __restrict__ qtab, const float* __restrict__ itab,
    const float* __restrict__ keymem,
    const float* __restrict__ Wv, const float* __restrict__ bv,
    const float* __restrict__ We, const float* __restrict__ be,
    const float* __restrict__ Wa, const float* __restrict__ ba,
    const float* __restrict__ Ws, const float* __restrict__ Wc,
    float* __restrict__ attn_tab, float* __restrict__ sq_tab,
    float* __restrict__ ead_tab, float* __restrict__ WsT, float* __restrict__ WcT) {
  const int bid = blockIdx.x;
  const int t = threadIdx.x;

  if (bid == NQ1) {  // ---- transposes ----
    for (int idx = t; idx < 64 * SD; idx += 64) {
      int i = idx / SD, j = idx % SD;
      WsT[j * 64 + i] = Ws[idx];
    }
    for (int idx = t; idx < SD * KK; idx += 64) {
      int j = idx / KK, c = idx % KK;
      WcT[c * SD + j] = Wc[idx];
    }
    return;
  }

  // ---- per-question block ----
  const int q = bid;
  __shared__ float qe[64];
  __shared__ float item[64];
  __shared__ float vq[64];
  qe[t] = qtab[q * KD + t];
  item[t] = itab[q * KD + t];
  __syncthreads();

  // attn softmax row
  float dot = 0.f;
  if (t < MM) {
#pragma unroll
    for (int i = 0; i < KD; ++i) dot = fmaf(qe[i], keymem[t * KD + i], dot);
  }
  float xv = (t < MM) ? dot : -1e30f;
#pragma unroll
  for (int off = 32; off; off >>= 1) xv = fmaxf(xv, __shfl_xor(xv, off));
  float p = (t < MM) ? __expf(dot - xv) : 0.f;
  float sum = p;
#pragma unroll
  for (int off = 32; off; off >>= 1) sum += __shfl_xor(sum, off);
  attn_tab[q * 64 + t] = p / sum;   // pad lanes (t>=50) write 0

  // sq row
  float sq = 0.f;
  if (t < SD) {
#pragma unroll
    for (int i = 0; i < KD; ++i) sq = fmaf(qe[i], Ws[(64 + i) * SD + t], sq);
  }
  sq_tab[q * 64 + t] = (t < SD) ? sq : 0.f;

  // vq = item @ Wv + bv (q-only part of value_embed)
  float v0 = bv[t];
#pragma unroll
  for (int i = 0; i < KD; ++i) v0 = fmaf(item[i], Wv[i * VD + t], v0);
  vq[t] = v0;
  __syncthreads();

  // se/sa = vq @ {We,Wa} + {be,ba}  (q-only parts of erase/add preactivations)
  float se = be[t], sa = ba[t];
#pragma unroll
  for (int i = 0; i < VD; ++i) {
    float x = vq[i];
    se = fmaf(x, We[i * VD + t], se);
    sa = fmaf(x, Wa[i * VD + t], sa);
  }

  // wrW[k]/wrA[k] = (Wv response-row k) @ {We,Wa} column t  (register-resident)
  float wrW[KK], wrA[KK];
#pragma unroll
  for (int k = 0; k < KK; ++k) {
    float accW = 0.f, accA = 0.f;
#pragma unroll
    for (int i = 0; i < VD; ++i) {
      float wv = Wv[(KD + k) * VD + i];
      accW = fmaf(wv, We[i * VD + t], accW);
      accA = fmaf(wv, Wa[i * VD + t], accA);
    }
    wrW[k] = accW;
    wrA[k] = accA;
  }

  // all 5 responses: ead rows
#pragma unroll
  for (int r = 0; r < KK; ++r) {
    float pe = 0.f, pa = 0.f;
#pragma unroll
    for (int k = 0; k < KK; ++k) {
      float rf = fmaxf(0.f, 1.f - fabsf((float)k - (float)r) * 0.25f);
      pe = fmaf(rf, wrW[k], pe);
      pa = fmaf(rf, wrA[k], pa);
    }
    float ser = se + pe, sar = sa + pa;
    float ex = __expf(2.f * sar);
    ead_tab[(q * KK + r) * 128 + 2 * t]     = 1.f / (1.f + __expf(-ser));
    ead_tab[(q * KK + r) * 128 + 2 * t + 1] = (ex - 1.f) / (ex + 1.f);
  }
}

// ---------------- kernel 2: scan (R14: SGPR a-rows + LDS ead/red, lgkm barriers) ----------------
__global__ __launch_bounds__(512) void k_scan(
    const int* __restrict__ qs, const int* __restrict__ rs,
    const float* __restrict__ attn_tab, const float* __restrict__ ead_tab,
    const float* __restrict__ init_vm, float* __restrict__ reads) {
  const int b = blockIdx.x;
  const int tid = threadIdx.x;
  const int w = tid >> 6;       // wave id 0..7 (m-slots w*8 .. w*8+7)
  const int v = tid & 63;       // value column
  const int mbase = w * 8;
  const int wb = w << 5;        // byte offset of wave's slice within a row

  __shared__ float red[2][WIN][NW][64];     // 32 KB partial read sums
  __shared__ v2f   eadbuf[2][WIN][64];      // 8 KB interleaved (e,ad) per v
  __shared__ __align__(16) int sidx_a[512]; // 2 KB per-step attn byte offsets

  const int* __restrict__ qb = qs + b * SS;
  const int* __restrict__ rb = rs + b * SS;
  float* __restrict__ outp = reads + (size_t)b * SS * 64;

  // ---- fill per-step attn byte offsets (entries 500..511 clamped) ----
  {
    int idx = (tid < SS) ? tid : (SS - 1);
    sidx_a[tid] = qb[idx] << 8;
  }

  // ---- prologue: stage window 0 ead; preload q/r ring for window 1 ----
  {
    int qp = qb[w], rp = rb[w];
    float2 ep = *(const float2*)(ead_tab + (qp * KK + rp) * 128 + 2 * v);
    eadbuf[0][w][v] = (v2f){ep.x, ep.y};
  }
  int q1 = qb[8 + w], r1 = rb[8 + w];

  v2f vm0, vm1, vm2, vm3;
  {
    int m = mbase;
    vm0.x = init_vm[(m + 0) * VD + v]; vm0.y = init_vm[(m + 1) * VD + v];
    vm1.x = init_vm[(m + 2) * VD + v]; vm1.y = init_vm[(m + 3) * VD + v];
    if (m + 4 < MM) { vm2.x = init_vm[(m + 4) * VD + v]; vm2.y = init_vm[(m + 5) * VD + v]; }
    else vm2 = (v2f)(0.f);
    if (m + 6 < MM) { vm3.x = init_vm[(m + 6) * VD + v]; vm3.y = init_vm[(m + 7) * VD + v]; }
    else vm3 = (v2f)(0.f);
  }
  __syncthreads();   // sidx_a visible to all waves

  // ---- load window-0 a-slices into SGPR buffer (8 x s_load_dwordx8) ----
  f32x8 arow[8];
  {
    int4 p0 = *(const int4*)&sidx_a[0];
    int4 p1 = *(const int4*)&sidx_a[4];
    uint32_t o0 = RL(p0.x + wb), o1 = RL(p0.y + wb);
    uint32_t o2 = RL(p0.z + wb), o3 = RL(p0.w + wb);
    uint32_t o4 = RL(p1.x + wb), o5 = RL(p1.y + wb);
    uint32_t o6 = RL(p1.z + wb), o7 = RL(p1.w + wb);
    SLOAD(arow[0], o0); SLOAD(arow[1], o1); SLOAD(arow[2], o2); SLOAD(arow[3], o3);
    SLOAD(arow[4], o4); SLOAD(arow[5], o5); SLOAD(arow[6], o6); SLOAD(arow[7], o7);
  }
  LGKM_BARRIER();   // drains s_loads + eadbuf staging
  SCHED_FENCE();

  v2f edr[2];

#define STEP(buf_, kk) {                                             \
    v2f ed = edr[(kk) & 1];                                          \
    if ((kk) < WIN - 2) edr[(kk) & 1] = eadbuf[buf_][(kk) + 2][v];   \
    v2f e2 = {ed.x, ed.x}, ad2 = {ed.y, ed.y};                       \
    v2f aL0 = {arow[kk][0], arow[kk][1]};                            \
    v2f aL1 = {arow[kk][2], arow[kk][3]};                            \
    v2f aH0 = {arow[kk][4], arow[kk][5]};                            \
    v2f aH1 = {arow[kk][6], arow[kk][7]};                            \
    v2f acc;                                                         \
    acc  = aL0 * vm0;  vm0 += aL0 * (ad2 - e2 * vm0);                \
    acc += aL1 * vm1;  vm1 += aL1 * (ad2 - e2 * vm1);                \
    acc += aH0 * vm2;  vm2 += aH0 * (ad2 - e2 * vm2);                \
    acc += aH1 * vm3;  vm3 += aH1 * (ad2 - e2 * vm3);                \
    red[buf_][kk][w][v] = acc.x + acc.y;                             \
    SLOAD(arow[kk], onext##kk);                                      \
  }

#define FLUSH(pbuf_, baserow_) {                                     \
    float sum = 0.f;                                                 \
    _Pragma("unroll")                                                \
    for (int wv = 0; wv < NW; ++wv) sum += red[pbuf_][w][wv][v];     \
    outp[(size_t)((baserow_) + w) * 64 + v] = sum;                   \
  }

  for (int wi = 0; wi < NWIN; ++wi) {
    const int buf = wi & 1;
    const int nb = buf ^ 1;

    // next-window a byte offsets (uniform b128 reads + readfirstlane)
    int4 p0 = *(const int4*)&sidx_a[(wi + 1) * 8];
    int4 p1 = *(const int4*)&sidx_a[(wi + 1) * 8 + 4];
    uint32_t onext0 = RL(p0.x + wb), onext1 = RL(p0.y + wb);
    uint32_t onext2 = RL(p0.z + wb), onext3 = RL(p0.w + wb);
    uint32_t onext4 = RL(p1.x + wb), onext5 = RL(p1.y + wb);
    uint32_t onext6 = RL(p1.z + wb), onext7 = RL(p1.w + wb);

    // edr preload for steps 0,1
    edr[0] = eadbuf[buf][0][v];
    edr[1] = eadbuf[buf][1][v];

    // flush previous window (reads red[nb]; store fire-and-forget)
    if (wi > 0) FLUSH(nb, (wi - 1) * WIN);

    // ead staging issue for window wi+1 (VMEM)
    float2 e_st = *(const float2*)(ead_tab + (q1 * KK + r1) * 128 + 2 * v);
    int i2 = (wi + 2) * WIN + w;
    i2 = (i2 < SS) ? i2 : (SS - 1);
    int q2 = qb[i2], r2 = rb[i2];

    // 8 steps; each consumes arow[k] then reloads it for window wi+1
    STEP(buf, 0) STEP(buf, 1) STEP(buf, 2) STEP(buf, 3)
    STEP(buf, 4) STEP(buf, 5) STEP(buf, 6) STEP(buf, 7)

    // ead staging write
    eadbuf[nb][w][v] = (v2f){e_st.x, e_st.y};
    q1 = q2; r1 = r2;

    LGKM_BARRIER();   // drains LDS ops AND this window's s_loads
    SCHED_FENCE();
  }

  // ---- tail: window 62 = steps 496..499, buf 0 (arow loaded in window 61) ----
  {
    uint32_t onext0, onext1, onext2, onext3;
    {
      int4 p0 = *(const int4*)&sidx_a[504];   // clamped entries, harmless reloads
      onext0 = RL(p0.x + wb); onext1 = RL(p0.y + wb);
      onext2 = RL(p0.z + wb); onext3 = RL(p0.w + wb);
    }
    edr[0] = eadbuf[0][0][v];
    edr[1] = eadbuf[0][1][v];
    FLUSH(1, (NWIN - 1) * WIN);              // flush window 61
    STEP(0, 0) STEP(0, 1) STEP(0, 2) STEP(0, 3)
    LGKM_BARRIER();
    SCHED_FENCE();
    if (w < (SS - NWIN * WIN)) {
      float sum = 0.f;
#pragma unroll
      for (int wv = 0; wv < NW; ++wv) sum += red[0][w][wv][v];
      outp[(size_t)(NWIN * WIN + w) * 64 + v] = sum;
    }
  }
#undef STEP
#undef FLUSH
}

// ---------------- kernel 3: summary + logits + softmax (float4 staging, packed f32) ----------------
__global__ __launch_bounds__(64) void k_out(
    const float* __restrict__ reads, const int* __restrict__ qs,
    const float* __restrict__ sq_tab, const float* __restrict__ WsT,
    const float* __restrict__ bs, const float* __restrict__ WcT,
    const float* __restrict__ bc,
    float* __restrict__ out_logits, float* __restrict__ out_probs) {
  __shared__ float xs[64 * 65];
  const int lane = threadIdx.x;
  const long rowbase = (long)blockIdx.x * 64;
  const float4* __restrict__ src4 = (const float4*)(reads + rowbase * 64);

  // stage 64 rows via float4 loads (1 KB/instr coalesced), scalar LDS writes
  const int rsub = lane >> 4;        // 0..3
  const int c4 = lane & 15;          // float4 column 0..15
#pragma unroll
  for (int it = 0; it < 16; ++it) {
    int row = it * 4 + rsub;
    float4 tt = src4[row * 16 + c4];
    float* dst = &xs[row * 65 + c4 * 4];
    dst[0] = tt.x; dst[1] = tt.y; dst[2] = tt.z; dst[3] = tt.w;
  }
  __syncthreads();

  v2f x2[32];
#pragma unroll
  for (int i = 0; i < 32; ++i)
    x2[i] = (v2f){xs[lane * 65 + 2 * i], xs[lane * 65 + 2 * i + 1]};

  const long row = rowbase + lane;
  const int q = qs[row];
  const float* __restrict__ sqrow = sq_tab + (long)q * 64;

  __attribute__((aligned(8))) float sm[SD];
#pragma unroll
  for (int j = 0; j < SD; ++j) {
    const v2f* __restrict__ wr2 = (const v2f*)(WsT + j * 64);  // uniform -> s_load
    v2f acc2 = (v2f)(0.f);
#pragma unroll
    for (int i = 0; i < 32; ++i) acc2 += x2[i] * wr2[i];
    float acc = acc2.x + acc2.y + bs[j] + sqrow[j];
    float ex = __expf(2.f * acc);
    sm[j] = (ex - 1.f) / (ex + 1.f);
  }

  float lg[KK];
  const v2f* __restrict__ sm2 = (const v2f*)sm;
#pragma unroll
  for (int c = 0; c < KK; ++c) {
    const v2f* __restrict__ wc2 = (const v2f*)(WcT + c * SD);  // uniform -> s_load
    v2f a2 = (v2f)(0.f);
#pragma unroll
    for (int j = 0; j < 25; ++j) a2 += sm2[j] * wc2[j];
    lg[c] = a2.x + a2.y + bc[c];
  }

  float mx = lg[0];
#pragma unroll
  for (int c = 1; c < KK; ++c) mx = fmaxf(mx, lg[c]);
  float p[KK], sum = 0.f;
#pragma unroll
  for (int c = 0; c < KK; ++c) { p[c] = __expf(lg[c] - mx); sum += p[c]; }
  float inv = 1.f / sum;
#pragma unroll
  for (int c = 0; c < KK; ++c) {
    out_logits[row * KK + c] = lg[c];
    out_probs[row * KK + c] = p[c] * inv;
  }
}

extern "C" void kernel_launch(void* const* d_in, const int* in_sizes, int n_in,
                              void* d_out, int out_size, void* d_ws, size_t ws_size,
                              hipStream_t stream) {
  const int*   questions  = (const int*)  d_in[0];
  const int*   responses  = (const int*)  d_in[1];
  const float* q_table    = (const float*)d_in[2];
  const float* item_table = (const float*)d_in[3];
  const float* Wv         = (const float*)d_in[4];
  const float* bv         = (const float*)d_in[5];
  const float* key_mem    = (const float*)d_in[6];
  const float* init_vm    = (const float*)d_in[7];
  const float* We         = (const float*)d_in[8];
  const float* be         = (const float*)d_in[9];
  const float* Wa         = (const float*)d_in[10];
  const float* ba         = (const float*)d_in[11];
  const float* Ws         = (const float*)d_in[12];
  const float* bs         = (const float*)d_in[13];
  const float* Wc         = (const float*)d_in[14];
  const float* bc         = (const float*)d_in[15];

  float* ws       = (float*)d_ws;
  float* attn_tab = ws + OFF_ATTN;
  float* sq_tab   = ws + OFF_SQ;
  float* ead_tab  = ws + OFF_EAD;
  float* WsT      = ws + OFF_WST;
  float* WcT      = ws + OFF_WCT;
  float* reads    = ws + OFF_READS;

  float* out_logits = (float*)d_out;
  float* out_probs  = out_logits + (size_t)BB * SS * KK;

  hipLaunchKernelGGL(k_tabs, dim3(NQ1 + 1), dim3(64), 0, stream,
                     q_table, item_table, key_mem, Wv, bv, We, be, Wa, ba, Ws, Wc,
                     attn_tab, sq_tab, ead_tab, WsT, WcT);
  hipLaunchKernelGGL(k_scan, dim3(BB), dim3(NW * 64), 0, stream,
                     questions, responses, attn_tab, ead_tab, init_vm, reads);
  hipLaunchKernelGGL(k_out, dim3(BB * SS / 64), dim3(64), 0, stream,
                     reads, questions, sq_tab, WsT, bs, WcT, bc,
                     out_logits, out_probs);
}

// Round 19
// 136.075 us; speedup vs baseline: 1.3385x; 1.1469x over previous
//
#include <hip/hip_runtime.h>
#include <hip/hip_bf16.h>
#include <math.h>

typedef float v2f __attribute__((ext_vector_type(2)));
typedef float f32x8 __attribute__((ext_vector_type(8)));

// Problem constants
#define NQ1 1001      // NQ+1 rows in embed tables
#define KK 5
#define MM 50
#define KD 64
#define VD 64
#define SD 50
#define BB 512
#define SS 500

#define NW 8          // waves per scan block
#define WIN 8         // scan steps per window
#define NWIN 62       // full windows (62*8 = 496; tail = 4 steps)

// Workspace layout (in floats)
#define OFF_ATTN   0                        // [1001][64] attn rows, cols 50..63 = 0
#define OFF_SQ     (OFF_ATTN + NQ1*64)      // [1001][64] q_embed @ Ws[64:128]
#define OFF_EAD    (OFF_SQ   + NQ1*64)      // [5005][128] interleaved (e,ad) per v
#define OFF_WST    (OFF_EAD  + NQ1*KK*128)  // [50][64] transposed top of Ws
#define OFF_WCT    (OFF_WST  + SD*64)       // [5][50] transposed Wc (pad to 256)
#define OFF_READS  (OFF_WCT  + 256)         // [512*500][64] bf16 (half the area used)

#define LGKM_BARRIER() asm volatile("s_waitcnt lgkmcnt(0)\n\ts_barrier" ::: "memory")
#define SCHED_FENCE() __builtin_amdgcn_sched_barrier(0)
#define RL(x_) __builtin_amdgcn_readfirstlane(x_)

// scalar load of one 32B attn slice: dst (8 SGPRs) <- attn_tab + byteoff
#define SLOAD(dst_, off_) \
  asm volatile("s_load_dwordx8 %0, %1, %2" : "=s"(dst_) : "s"(attn_tab), "s"(off_))

// ---------------- kernel 1: all tables, fused (per-q: attn/sq/ead rows; +transposes) ----------------
__global__ __launch_bounds__(64) void k_tabs(
    const float* __restrict__ qtab, const float* __restrict__ itab,
    const float* __restrict__ keymem,
    const float* __restrict__ Wv, const float* __restrict__ bv,
    const float* __restrict__ We, const float* __restrict__ be,
    const float* __restrict__ Wa, const float* __restrict__ ba,
    const float* __restrict__ Ws, const float* __restrict__ Wc,
    float* __restrict__ attn_tab, float* __restrict__ sq_tab,
    float* __restrict__ ead_tab, float* __restrict__ WsT, float* __restrict__ WcT) {
  const int bid = blockIdx.x;
  const int t = threadIdx.x;

  if (bid == NQ1) {  // ---- transposes ----
    for (int idx = t; idx < 64 * SD; idx += 64) {
      int i = idx / SD, j = idx % SD;
      WsT[j * 64 + i] = Ws[idx];
    }
    for (int idx = t; idx < SD * KK; idx += 64) {
      int j = idx / KK, c = idx % KK;
      WcT[c * SD + j] = Wc[idx];
    }
    return;
  }

  // ---- per-question block ----
  const int q = bid;
  __shared__ float qe[64];
  __shared__ float item[64];
  __shared__ float vq[64];
  qe[t] = qtab[q * KD + t];
  item[t] = itab[q * KD + t];
  __syncthreads();

  // attn softmax row
  float dot = 0.f;
  if (t < MM) {
#pragma unroll
    for (int i = 0; i < KD; ++i) dot = fmaf(qe[i], keymem[t * KD + i], dot);
  }
  float xv = (t < MM) ? dot : -1e30f;
#pragma unroll
  for (int off = 32; off; off >>= 1) xv = fmaxf(xv, __shfl_xor(xv, off));
  float p = (t < MM) ? __expf(dot - xv) : 0.f;
  float sum = p;
#pragma unroll
  for (int off = 32; off; off >>= 1) sum += __shfl_xor(sum, off);
  attn_tab[q * 64 + t] = p / sum;   // pad lanes (t>=50) write 0

  // sq row
  float sq = 0.f;
  if (t < SD) {
#pragma unroll
    for (int i = 0; i < KD; ++i) sq = fmaf(qe[i], Ws[(64 + i) * SD + t], sq);
  }
  sq_tab[q * 64 + t] = (t < SD) ? sq : 0.f;

  // vq = item @ Wv + bv (q-only part of value_embed)
  float v0 = bv[t];
#pragma unroll
  for (int i = 0; i < KD; ++i) v0 = fmaf(item[i], Wv[i * VD + t], v0);
  vq[t] = v0;
  __syncthreads();

  // se/sa = vq @ {We,Wa} + {be,ba}  (q-only parts of erase/add preactivations)
  float se = be[t], sa = ba[t];
#pragma unroll
  for (int i = 0; i < VD; ++i) {
    float x = vq[i];
    se = fmaf(x, We[i * VD + t], se);
    sa = fmaf(x, Wa[i * VD + t], sa);
  }

  // wrW[k]/wrA[k] = (Wv response-row k) @ {We,Wa} column t  (register-resident)
  float wrW[KK], wrA[KK];
#pragma unroll
  for (int k = 0; k < KK; ++k) {
    float accW = 0.f, accA = 0.f;
#pragma unroll
    for (int i = 0; i < VD; ++i) {
      float wv = Wv[(KD + k) * VD + i];
      accW = fmaf(wv, We[i * VD + t], accW);
      accA = fmaf(wv, Wa[i * VD + t], accA);
    }
    wrW[k] = accW;
    wrA[k] = accA;
  }

  // all 5 responses: ead rows
#pragma unroll
  for (int r = 0; r < KK; ++r) {
    float pe = 0.f, pa = 0.f;
#pragma unroll
    for (int k = 0; k < KK; ++k) {
      float rf = fmaxf(0.f, 1.f - fabsf((float)k - (float)r) * 0.25f);
      pe = fmaf(rf, wrW[k], pe);
      pa = fmaf(rf, wrA[k], pa);
    }
    float ser = se + pe, sar = sa + pa;
    float ex = __expf(2.f * sar);
    ead_tab[(q * KK + r) * 128 + 2 * t]     = 1.f / (1.f + __expf(-ser));
    ead_tab[(q * KK + r) * 128 + 2 * t + 1] = (ex - 1.f) / (ex + 1.f);
  }
}

// ---------------- kernel 2: scan (R14: SGPR a-rows + LDS ead/red, lgkm barriers; bf16 out) ----------------
__global__ __launch_bounds__(512) void k_scan(
    const int* __restrict__ qs, const int* __restrict__ rs,
    const float* __restrict__ attn_tab, const float* __restrict__ ead_tab,
    const float* __restrict__ init_vm, __hip_bfloat16* __restrict__ reads) {
  const int b = blockIdx.x;
  const int tid = threadIdx.x;
  const int w = tid >> 6;       // wave id 0..7 (m-slots w*8 .. w*8+7)
  const int v = tid & 63;       // value column
  const int mbase = w * 8;
  const int wb = w << 5;        // byte offset of wave's slice within a row

  __shared__ float red[2][WIN][NW][64];     // 32 KB partial read sums
  __shared__ v2f   eadbuf[2][WIN][64];      // 8 KB interleaved (e,ad) per v
  __shared__ __align__(16) int sidx_a[512]; // 2 KB per-step attn byte offsets

  const int* __restrict__ qb = qs + b * SS;
  const int* __restrict__ rb = rs + b * SS;
  __hip_bfloat16* __restrict__ outp = reads + (size_t)b * SS * 64;

  // ---- fill per-step attn byte offsets (entries 500..511 clamped) ----
  {
    int idx = (tid < SS) ? tid : (SS - 1);
    sidx_a[tid] = qb[idx] << 8;
  }

  // ---- prologue: stage window 0 ead; preload q/r ring for window 1 ----
  {
    int qp = qb[w], rp = rb[w];
    float2 ep = *(const float2*)(ead_tab + (qp * KK + rp) * 128 + 2 * v);
    eadbuf[0][w][v] = (v2f){ep.x, ep.y};
  }
  int q1 = qb[8 + w], r1 = rb[8 + w];

  v2f vm0, vm1, vm2, vm3;
  {
    int m = mbase;
    vm0.x = init_vm[(m + 0) * VD + v]; vm0.y = init_vm[(m + 1) * VD + v];
    vm1.x = init_vm[(m + 2) * VD + v]; vm1.y = init_vm[(m + 3) * VD + v];
    if (m + 4 < MM) { vm2.x = init_vm[(m + 4) * VD + v]; vm2.y = init_vm[(m + 5) * VD + v]; }
    else vm2 = (v2f)(0.f);
    if (m + 6 < MM) { vm3.x = init_vm[(m + 6) * VD + v]; vm3.y = init_vm[(m + 7) * VD + v]; }
    else vm3 = (v2f)(0.f);
  }
  __syncthreads();   // sidx_a visible to all waves

  // ---- load window-0 a-slices into SGPR buffer (8 x s_load_dwordx8) ----
  f32x8 arow[8];
  {
    int4 p0 = *(const int4*)&sidx_a[0];
    int4 p1 = *(const int4*)&sidx_a[4];
    uint32_t o0 = RL(p0.x + wb), o1 = RL(p0.y + wb);
    uint32_t o2 = RL(p0.z + wb), o3 = RL(p0.w + wb);
    uint32_t o4 = RL(p1.x + wb), o5 = RL(p1.y + wb);
    uint32_t o6 = RL(p1.z + wb), o7 = RL(p1.w + wb);
    SLOAD(arow[0], o0); SLOAD(arow[1], o1); SLOAD(arow[2], o2); SLOAD(arow[3], o3);
    SLOAD(arow[4], o4); SLOAD(arow[5], o5); SLOAD(arow[6], o6); SLOAD(arow[7], o7);
  }
  LGKM_BARRIER();   // drains s_loads + eadbuf staging
  SCHED_FENCE();

  v2f edr[2];

#define STEP(buf_, kk) {                                             \
    v2f ed = edr[(kk) & 1];                                          \
    if ((kk) < WIN - 2) edr[(kk) & 1] = eadbuf[buf_][(kk) + 2][v];   \
    v2f e2 = {ed.x, ed.x}, ad2 = {ed.y, ed.y};                       \
    v2f aL0 = {arow[kk][0], arow[kk][1]};                            \
    v2f aL1 = {arow[kk][2], arow[kk][3]};                            \
    v2f aH0 = {arow[kk][4], arow[kk][5]};                            \
    v2f aH1 = {arow[kk][6], arow[kk][7]};                            \
    v2f acc;                                                         \
    acc  = aL0 * vm0;  vm0 += aL0 * (ad2 - e2 * vm0);                \
    acc += aL1 * vm1;  vm1 += aL1 * (ad2 - e2 * vm1);                \
    acc += aH0 * vm2;  vm2 += aH0 * (ad2 - e2 * vm2);                \
    acc += aH1 * vm3;  vm3 += aH1 * (ad2 - e2 * vm3);                \
    red[buf_][kk][w][v] = acc.x + acc.y;                             \
    SLOAD(arow[kk], onext##kk);                                      \
  }

#define FLUSH(pbuf_, baserow_) {                                     \
    float sum = 0.f;                                                 \
    _Pragma("unroll")                                                \
    for (int wv = 0; wv < NW; ++wv) sum += red[pbuf_][w][wv][v];     \
    outp[(size_t)((baserow_) + w) * 64 + v] = __float2bfloat16(sum); \
  }

  for (int wi = 0; wi < NWIN; ++wi) {
    const int buf = wi & 1;
    const int nb = buf ^ 1;

    // next-window a byte offsets (uniform b128 reads + readfirstlane)
    int4 p0 = *(const int4*)&sidx_a[(wi + 1) * 8];
    int4 p1 = *(const int4*)&sidx_a[(wi + 1) * 8 + 4];
    uint32_t onext0 = RL(p0.x + wb), onext1 = RL(p0.y + wb);
    uint32_t onext2 = RL(p0.z + wb), onext3 = RL(p0.w + wb);
    uint32_t onext4 = RL(p1.x + wb), onext5 = RL(p1.y + wb);
    uint32_t onext6 = RL(p1.z + wb), onext7 = RL(p1.w + wb);

    // edr preload for steps 0,1
    edr[0] = eadbuf[buf][0][v];
    edr[1] = eadbuf[buf][1][v];

    // flush previous window (reads red[nb]; store fire-and-forget)
    if (wi > 0) FLUSH(nb, (wi - 1) * WIN);

    // ead staging issue for window wi+1 (VMEM)
    float2 e_st = *(const float2*)(ead_tab + (q1 * KK + r1) * 128 + 2 * v);
    int i2 = (wi + 2) * WIN + w;
    i2 = (i2 < SS) ? i2 : (SS - 1);
    int q2 = qb[i2], r2 = rb[i2];

    // 8 steps; each consumes arow[k] then reloads it for window wi+1
    STEP(buf, 0) STEP(buf, 1) STEP(buf, 2) STEP(buf, 3)
    STEP(buf, 4) STEP(buf, 5) STEP(buf, 6) STEP(buf, 7)

    // ead staging write
    eadbuf[nb][w][v] = (v2f){e_st.x, e_st.y};
    q1 = q2; r1 = r2;

    LGKM_BARRIER();   // drains LDS ops AND this window's s_loads
    SCHED_FENCE();
  }

  // ---- tail: window 62 = steps 496..499, buf 0 (arow loaded in window 61) ----
  {
    uint32_t onext0, onext1, onext2, onext3;
    {
      int4 p0 = *(const int4*)&sidx_a[504];   // clamped entries, harmless reloads
      onext0 = RL(p0.x + wb); onext1 = RL(p0.y + wb);
      onext2 = RL(p0.z + wb); onext3 = RL(p0.w + wb);
    }
    edr[0] = eadbuf[0][0][v];
    edr[1] = eadbuf[0][1][v];
    FLUSH(1, (NWIN - 1) * WIN);              // flush window 61
    STEP(0, 0) STEP(0, 1) STEP(0, 2) STEP(0, 3)
    LGKM_BARRIER();
    SCHED_FENCE();
    if (w < (SS - NWIN * WIN)) {
      float sum = 0.f;
#pragma unroll
      for (int wv = 0; wv < NW; ++wv) sum += red[0][w][wv][v];
      outp[(size_t)(NWIN * WIN + w) * 64 + v] = __float2bfloat16(sum);
    }
  }
#undef STEP
#undef FLUSH
}

// ---------------- kernel 3: summary + logits + softmax (bf16 row loads, no LDS) ----------------
__global__ __launch_bounds__(64) void k_out(
    const __hip_bfloat16* __restrict__ reads, const int* __restrict__ qs,
    const float* __restrict__ sq_tab, const float* __restrict__ WsT,
    const float* __restrict__ bs, const float* __restrict__ WcT,
    const float* __restrict__ bc,
    float* __restrict__ out_logits, float* __restrict__ out_probs) {
  const int lane = threadIdx.x;
  const long row = (long)blockIdx.x * 64 + lane;

  // each lane loads its own 128B bf16 row: 8 x uint4 (wave covers 8KB dense)
  const uint4* __restrict__ src = (const uint4*)(reads + (size_t)row * 64);
  v2f x2[32];
#pragma unroll
  for (int c = 0; c < 8; ++c) {
    uint4 u = src[c];
    x2[c * 4 + 0] = (v2f){__uint_as_float(u.x << 16), __uint_as_float(u.x & 0xFFFF0000u)};
    x2[c * 4 + 1] = (v2f){__uint_as_float(u.y << 16), __uint_as_float(u.y & 0xFFFF0000u)};
    x2[c * 4 + 2] = (v2f){__uint_as_float(u.z << 16), __uint_as_float(u.z & 0xFFFF0000u)};
    x2[c * 4 + 3] = (v2f){__uint_as_float(u.w << 16), __uint_as_float(u.w & 0xFFFF0000u)};
  }

  const int q = qs[row];
  const float* __restrict__ sqrow = sq_tab + (long)q * 64;

  __attribute__((aligned(8))) float sm[SD];
#pragma unroll
  for (int j = 0; j < SD; ++j) {
    const v2f* __restrict__ wr2 = (const v2f*)(WsT + j * 64);  // uniform -> s_load
    v2f acc2 = (v2f)(0.f);
#pragma unroll
    for (int i = 0; i < 32; ++i) acc2 += x2[i] * wr2[i];
    float acc = acc2.x + acc2.y + bs[j] + sqrow[j];
    float ex = __expf(2.f * acc);
    sm[j] = (ex - 1.f) / (ex + 1.f);
  }

  float lg[KK];
  const v2f* __restrict__ sm2 = (const v2f*)sm;
#pragma unroll
  for (int c = 0; c < KK; ++c) {
    const v2f* __restrict__ wc2 = (const v2f*)(WcT + c * SD);  // uniform -> s_load
    v2f a2 = (v2f)(0.f);
#pragma unroll
    for (int j = 0; j < 25; ++j) a2 += sm2[j] * wc2[j];
    lg[c] = a2.x + a2.y + bc[c];
  }

  float mx = lg[0];
#pragma unroll
  for (int c = 1; c < KK; ++c) mx = fmaxf(mx, lg[c]);
  float p[KK], sum = 0.f;
#pragma unroll
  for (int c = 0; c < KK; ++c) { p[c] = __expf(lg[c] - mx); sum += p[c]; }
  float inv = 1.f / sum;
#pragma unroll
  for (int c = 0; c < KK; ++c) {
    out_logits[row * KK + c] = lg[c];
    out_probs[row * KK + c] = p[c] * inv;
  }
}

extern "C" void kernel_launch(void* const* d_in, const int* in_sizes, int n_in,
                              void* d_out, int out_size, void* d_ws, size_t ws_size,
                              hipStream_t stream) {
  const int*   questions  = (const int*)  d_in[0];
  const int*   responses  = (const int*)  d_in[1];
  const float* q_table    = (const float*)d_in[2];
  const float* item_table = (const float*)d_in[3];
  const float* Wv         = (const float*)d_in[4];
  const float* bv         = (const float*)d_in[5];
  const float* key_mem    = (const float*)d_in[6];
  const float* init_vm    = (const float*)d_in[7];
  const float* We         = (const float*)d_in[8];
  const float* be         = (const float*)d_in[9];
  const float* Wa         = (const float*)d_in[10];
  const float* ba         = (const float*)d_in[11];
  const float* Ws         = (const float*)d_in[12];
  const float* bs         = (const float*)d_in[13];
  const float* Wc         = (const float*)d_in[14];
  const float* bc         = (const float*)d_in[15];

  float* ws       = (float*)d_ws;
  float* attn_tab = ws + OFF_ATTN;
  float* sq_tab   = ws + OFF_SQ;
  float* ead_tab  = ws + OFF_EAD;
  float* WsT      = ws + OFF_WST;
  float* WcT      = ws + OFF_WCT;
  __hip_bfloat16* reads = (__hip_bfloat16*)(ws + OFF_READS);

  float* out_logits = (float*)d_out;
  float* out_probs  = out_logits + (size_t)BB * SS * KK;

  hipLaunchKernelGGL(k_tabs, dim3(NQ1 + 1), dim3(64), 0, stream,
                     q_table, item_table, key_mem, Wv, bv, We, be, Wa, ba, Ws, Wc,
                     attn_tab, sq_tab, ead_tab, WsT, WcT);
  hipLaunchKernelGGL(k_scan, dim3(BB), dim3(NW * 64), 0, stream,
                     questions, responses, attn_tab, ead_tab, init_vm, reads);
  hipLaunchKernelGGL(k_out, dim3(BB * SS / 64), dim3(64), 0, stream,
                     reads, questions, sq_tab, WsT, bs, WcT, bc,
                     out_logits, out_probs);
}